// Round 14
// baseline (100.447 us; speedup 1.0000x reference)
//
#include <hip/hip_runtime.h>
#include <math.h>

namespace {
constexpr int S_N   = 4096;
constexpr int D_N   = 128;
constexpr int DD_N  = 64;
constexpr int REL_N = 8;
constexpr int R_N   = 512;
constexpr int NTOT  = S_N * REL_N;                        // 32768
constexpr int ROWLEN = R_N + NTOT;                        // 33280
constexpr long long FC_IN_N = (long long)DD_N * ROWLEN;   // 2,129,920
constexpr int NCH   = 8;                                  // col chunks per w-row
constexpr int CHUNK2 = (int)(FC_IN_N / NCH);              // 266,240 floats = 1040 KB = exactly 8 h-rows
constexpr int NF4   = CHUNK2 / 4;                         // 66,560 float4 per chunk (8 x 8320)
constexpr int RPB   = 2;                                  // output rows per k_mv block
constexpr int KG_N  = DD_N / RPB;                         // 32 k-groups
constexpr int NBLK3 = NCH * KG_N;                         // 256 blocks (1/CU, mult of 8)
constexpr int SEP   = 132;                                // padded LDS row stride (floats)
typedef float floatx4 __attribute__((ext_vector_type(4)));

__device__ __forceinline__ float dot4(const float4& a, const float4& b) {
    return a.x*b.x + a.y*b.y + a.z*b.z + a.w*b.w;
}
}

// Fused pre-kernel, 256 blocks x 16 symptoms each:
//   DE[dd][s] = dise[dd].embed[s]
//   xinv[s*8+r] = mask[s]&&sq>0 ? rsqrt(||e_s||^2 + 2 e_s.rel_r + ||rel_r||^2) : 0
//   block 0 also: dsc[dd]=1/||dise[dd]||, DR[dd][r]=dise[dd].rel[r]
__global__ __launch_bounds__(256) void k_pre(const int* __restrict__ inputs,
                                             const float* __restrict__ dise,
                                             const float* __restrict__ embed,
                                             const float* __restrict__ rel,
                                             float* __restrict__ DE,
                                             float* __restrict__ DR,
                                             float* __restrict__ dsc_g,
                                             float* __restrict__ xinv) {
    __shared__ float sd[DD_N * 129];                  // dise, pad 129 (2-way = free)
    __shared__ __align__(16) float se[16 * SEP];      // embed tile, stride 132 (conflict-free groups)
    __shared__ __align__(16) float sr[REL_N * SEP];   // rel, stride 132
    __shared__ float rr[REL_N];
    const int tid  = threadIdx.x;
    const int lane = tid & 63;
    const int wave = tid >> 6;
    const int s0   = blockIdx.x * 16;

    for (int i = tid; i < DD_N * D_N; i += 256)
        sd[(i >> 7) * 129 + (i & 127)] = dise[i];
    for (int i = tid; i < 16 * 32; i += 256) {        // 512 float4s of embed tile
        const int row = i >> 5, col = i & 31;
        *reinterpret_cast<float4*>(&se[row * SEP + col * 4]) =
            reinterpret_cast<const float4*>(embed + (size_t)s0 * D_N)[i];
    }
    if (tid < REL_N * 32) {                           // 256 float4s of rel
        const int row = tid >> 5, col = tid & 31;
        *reinterpret_cast<float4*>(&sr[row * SEP + col * 4]) =
            reinterpret_cast<const float4*>(rel)[tid];
    }
    __syncthreads();

    if (tid < REL_N) {
        float a = 0.f;
        for (int e = 0; e < D_N; ++e) { float v = sr[tid * SEP + e]; a += v * v; }
        rr[tid] = a;
    }

    float dw[D_N];
    float dsq = 0.f;
    #pragma unroll
    for (int e = 0; e < D_N; ++e) {
        dw[e] = sd[lane * 129 + e];
        dsq += dw[e] * dw[e];
    }
    const float dsc = rsqrtf(dsq);

    if (blockIdx.x == 0) {
        if (wave == 0) dsc_g[lane] = dsc;
        #pragma unroll
        for (int rr2 = 0; rr2 < 2; ++rr2) {
            const int r = wave * 2 + rr2;
            float a = 0.f;
            #pragma unroll
            for (int e = 0; e < D_N; ++e) a += dw[e] * sr[r * SEP + e];
            DR[lane * REL_N + r] = a;
        }
    }

    // DE: wave handles s-locals [wave*4, wave*4+4); se reads broadcast within 64-lane groups
    {
        float4 o;
        float* op = reinterpret_cast<float*>(&o);
        #pragma unroll
        for (int jj = 0; jj < 4; ++jj) {
            const int nl = wave * 4 + jj;
            const float4* xr = reinterpret_cast<const float4*>(&se[nl * SEP]);
            float a0 = 0.f, a1 = 0.f, a2 = 0.f, a3 = 0.f;
            #pragma unroll
            for (int i = 0; i < 32; i += 4) {
                float4 x0 = xr[i], x1 = xr[i + 1], x2 = xr[i + 2], x3 = xr[i + 3];
                a0 += dw[4*i+ 0]*x0.x + dw[4*i+ 1]*x0.y + dw[4*i+ 2]*x0.z + dw[4*i+ 3]*x0.w;
                a1 += dw[4*i+ 4]*x1.x + dw[4*i+ 5]*x1.y + dw[4*i+ 6]*x1.z + dw[4*i+ 7]*x1.w;
                a2 += dw[4*i+ 8]*x2.x + dw[4*i+ 9]*x2.y + dw[4*i+10]*x2.z + dw[4*i+11]*x2.w;
                a3 += dw[4*i+12]*x3.x + dw[4*i+13]*x3.y + dw[4*i+14]*x3.z + dw[4*i+15]*x3.w;
            }
            op[jj] = a0 + a1 + a2 + a3;
        }
        *reinterpret_cast<float4*>(DE + (size_t)lane * S_N + s0 + wave * 4) = o;
    }

    __syncthreads();   // rr ready

    // xinv: 128 threads, one (s-local, r) pair each
    if (tid < 128) {
        const int sl = tid >> 3, r = tid & 7;
        const float4* ev4 = reinterpret_cast<const float4*>(&se[sl * SEP]);
        const float4* rv4 = reinterpret_cast<const float4*>(&sr[r * SEP]);
        float ee = 0.f, er = 0.f;
        #pragma unroll
        for (int i = 0; i < 32; ++i) {
            float4 ev = ev4[i], rv = rv4[i];
            ee += dot4(ev, ev);
            er += dot4(ev, rv);
        }
        const float sq = ee + 2.f * er + rr[r];
        const bool m = (inputs[s0 + sl] != 0);
        xinv[(size_t)(s0 + sl) * REL_N + r] = (m && sq > 0.f) ? rsqrtf(sq) : 0.f;
    }
}

// block (kg, c): out rows kg*2..kg*2+1, cols [c*266240, (c+1)*266240) = h rows 8c..8c+7.
// 512 streams of 1040 KB (vs 1024 x 520 KB) — third halving of stream count.
// h synthesized inline from L2-resident xinv/DE/DR/rf; round-7 interleave; nt on w.
__global__ __launch_bounds__(512, 1) void k_mv(const float* __restrict__ fcw,
                                               const float* __restrict__ rf,
                                               const float* __restrict__ DE,
                                               const float* __restrict__ DR,
                                               const float* __restrict__ dsc_g,
                                               const float* __restrict__ xinv,
                                               float* __restrict__ partials) {
    const int tid = threadIdx.x;
    // bijective XCD swizzle (256 % 8 == 0): chunk c's 32 blocks cluster on one XCD
    const int swz = (blockIdx.x & 7) * (NBLK3 / 8) + (blockIdx.x >> 3);
    const int c  = swz >> 5;      // 0..7
    const int kg = swz & 31;      // 0..31

    const floatx4* wp = reinterpret_cast<const floatx4*>(fcw)
                        + (size_t)(kg * RPB) * (FC_IN_N / 4) + (size_t)c * NF4;
    const float4* xv4 = reinterpret_cast<const float4*>(xinv);

    float acc[RPB];
    #pragma unroll
    for (int j = 0; j < RPB; ++j) acc[j] = 0.f;

    #pragma unroll
    for (int half = 0; half < 8; ++half) {
        const int dd = 8 * c + half;
        const float dscv = dsc_g[dd];
        const float4 drlo = reinterpret_cast<const float4*>(DR)[dd * 2];
        const float4 drhi = reinterpret_cast<const float4*>(DR)[dd * 2 + 1];
        const float4 drv = (tid & 1) ? drhi : drlo;   // r-base = 4*(tid&1), thread-constant
        const float* DEp = DE + (size_t)dd * S_N;
        const int wbase = half * (ROWLEN / 4);        // half * 8320

        // rules columns: 128 f4 of this row
        if (tid < 128) {
            float4 hv = reinterpret_cast<const float4*>(rf)[dd * 128 + tid];
            const int idx = wbase + tid;
            #pragma unroll
            for (int j = 0; j < RPB; ++j) {
                floatx4 w = __builtin_nontemporal_load(wp + (size_t)j * (FC_IN_N / 4) + idx);
                acc[j] += w.x * hv.x + w.y * hv.y + w.z * hv.z + w.w * hv.w;
            }
        }

        // kg columns: exactly 16 x 512 f4 per row
        #pragma unroll 2
        for (int i = 0; i < 16; ++i) {
            const int col4k = i * 512 + tid;          // kg-local f4 index, 0..8191
            const int idx = wbase + 128 + col4k;
            const float de = DEp[col4k >> 1];         // s = n>>3 = col4k>>1
            const float4 xv = xv4[col4k];
            float4 hv;
            hv.x = dscv * xv.x * (de + drv.x);
            hv.y = dscv * xv.y * (de + drv.y);
            hv.z = dscv * xv.z * (de + drv.z);
            hv.w = dscv * xv.w * (de + drv.w);
            #pragma unroll
            for (int j = 0; j < RPB; ++j) {
                floatx4 w = __builtin_nontemporal_load(wp + (size_t)j * (FC_IN_N / 4) + idx);
                acc[j] += w.x * hv.x + w.y * hv.y + w.z * hv.z + w.w * hv.w;
            }
        }
    }

    #pragma unroll
    for (int m = 32; m >= 1; m >>= 1) {
        #pragma unroll
        for (int j = 0; j < RPB; ++j) acc[j] += __shfl_xor(acc[j], m);
    }
    __shared__ float red[8][RPB];
    if ((tid & 63) == 0) {
        const int wv = tid >> 6;
        #pragma unroll
        for (int j = 0; j < RPB; ++j) red[wv][j] = acc[j];
    }
    __syncthreads();
    if (tid < RPB) {
        float s = 0.f;
        #pragma unroll
        for (int wv = 0; wv < 8; ++wv) s += red[wv][tid];
        // partials[swz*RPB + j] == partials[c*64 + kg*2 + j]
        partials[(size_t)swz * RPB + tid] = s;
    }
}

// out[k] = sigmoid(fc_b[k] + sum_c partials[c*64 + k])
__global__ __launch_bounds__(256) void k_fin(const float* __restrict__ partials,
                                             const float* __restrict__ fcb,
                                             float* __restrict__ out) {
    const int tid = threadIdx.x;
    const int k = tid & 63, g = tid >> 6;
    float s = 0.f;
    for (int b = g; b < NCH; b += 4) s += partials[(size_t)b * 64 + k];
    __shared__ float red[4][64];
    red[g][k] = s;
    __syncthreads();
    if (tid < 64) {
        float t = red[0][tid] + red[1][tid] + red[2][tid] + red[3][tid] + fcb[tid];
        out[tid] = 1.0f / (1.0f + expf(-t));
    }
}

extern "C" void kernel_launch(void* const* d_in, const int* in_sizes, int n_in,
                              void* d_out, int out_size, void* d_ws, size_t ws_size,
                              hipStream_t stream) {
    const int*   inputs = (const int*)  d_in[0];
    const float* rf     = (const float*)d_in[1];
    const float* embed  = (const float*)d_in[2];
    const float* rel    = (const float*)d_in[3];
    const float* dise   = (const float*)d_in[4];
    const float* fcw    = (const float*)d_in[5];
    const float* fcb    = (const float*)d_in[6];
    float* out = (float*)d_out;

    // ws layout (floats): partials[NCH*64] | DE[64*4096] | DR[64*8] | dsc[64] | xinv[32768]
    float* ws = (float*)d_ws;
    float* partials = ws;
    float* DE       = partials + NCH * 64;
    float* DR       = DE + (size_t)DD_N * S_N;
    float* dsc_g    = DR + DD_N * REL_N;
    float* xinv     = dsc_g + 64;

    hipLaunchKernelGGL(k_pre, dim3(S_N / 16), dim3(256), 0, stream,
                       inputs, dise, embed, rel, DE, DR, dsc_g, xinv);
    hipLaunchKernelGGL(k_mv,  dim3(NBLK3),    dim3(512), 0, stream,
                       fcw, rf, DE, DR, dsc_g, xinv, partials);
    hipLaunchKernelGGL(k_fin, dim3(1),        dim3(256), 0, stream, partials, fcb, out);
}

// Round 15
// 98.643 us; speedup vs baseline: 1.0183x; 1.0183x over previous
//
#include <hip/hip_runtime.h>
#include <math.h>

namespace {
constexpr int S_N   = 4096;
constexpr int D_N   = 128;
constexpr int DD_N  = 64;
constexpr int REL_N = 8;
constexpr int R_N   = 512;
constexpr int NTOT  = S_N * REL_N;                        // 32768
constexpr int ROWLEN = R_N + NTOT;                        // 33280
constexpr long long FC_IN_N = (long long)DD_N * ROWLEN;   // 2,129,920
constexpr int NCH   = 16;                                 // col chunks per w-row (measured optimum)
constexpr int CHUNK2 = (int)(FC_IN_N / NCH);              // 133,120 floats = 520 KB = exactly 4 h-rows
constexpr int NF4   = CHUNK2 / 4;                         // 33,280 float4 per chunk (4 x 8320)
constexpr int RPB   = 4;                                  // output rows per k_mv block
constexpr int KG_N  = DD_N / RPB;                         // 16 k-groups
constexpr int NBLK3 = NCH * KG_N;                         // 256 blocks (1/CU, mult of 8)
constexpr int SEP   = 132;                                // padded LDS row stride (floats)
typedef float floatx4 __attribute__((ext_vector_type(4)));

__device__ __forceinline__ float dot4(const float4& a, const float4& b) {
    return a.x*b.x + a.y*b.y + a.z*b.z + a.w*b.w;
}
}

// Fused pre-kernel, 256 blocks x 16 symptoms each:
//   DE[dd][s] = dise[dd].embed[s]
//   xinv[s*8+r] = mask[s]&&sq>0 ? rsqrt(||e_s||^2 + 2 e_s.rel_r + ||rel_r||^2) : 0
//   block 0 also: dsc[dd]=1/||dise[dd]||, DR[dd][r]=dise[dd].rel[r]
__global__ __launch_bounds__(256) void k_pre(const int* __restrict__ inputs,
                                             const float* __restrict__ dise,
                                             const float* __restrict__ embed,
                                             const float* __restrict__ rel,
                                             float* __restrict__ DE,
                                             float* __restrict__ DR,
                                             float* __restrict__ dsc_g,
                                             float* __restrict__ xinv) {
    __shared__ float sd[DD_N * 129];                  // dise, pad 129 (2-way = free)
    __shared__ __align__(16) float se[16 * SEP];      // embed tile, stride 132 (conflict-free groups)
    __shared__ __align__(16) float sr[REL_N * SEP];   // rel, stride 132
    __shared__ float rr[REL_N];
    const int tid  = threadIdx.x;
    const int lane = tid & 63;
    const int wave = tid >> 6;
    const int s0   = blockIdx.x * 16;

    for (int i = tid; i < DD_N * D_N; i += 256)
        sd[(i >> 7) * 129 + (i & 127)] = dise[i];
    for (int i = tid; i < 16 * 32; i += 256) {        // 512 float4s of embed tile
        const int row = i >> 5, col = i & 31;
        *reinterpret_cast<float4*>(&se[row * SEP + col * 4]) =
            reinterpret_cast<const float4*>(embed + (size_t)s0 * D_N)[i];
    }
    if (tid < REL_N * 32) {                           // 256 float4s of rel
        const int row = tid >> 5, col = tid & 31;
        *reinterpret_cast<float4*>(&sr[row * SEP + col * 4]) =
            reinterpret_cast<const float4*>(rel)[tid];
    }
    __syncthreads();

    if (tid < REL_N) {
        float a = 0.f;
        for (int e = 0; e < D_N; ++e) { float v = sr[tid * SEP + e]; a += v * v; }
        rr[tid] = a;
    }

    float dw[D_N];
    float dsq = 0.f;
    #pragma unroll
    for (int e = 0; e < D_N; ++e) {
        dw[e] = sd[lane * 129 + e];
        dsq += dw[e] * dw[e];
    }
    const float dsc = rsqrtf(dsq);

    if (blockIdx.x == 0) {
        if (wave == 0) dsc_g[lane] = dsc;
        #pragma unroll
        for (int rr2 = 0; rr2 < 2; ++rr2) {
            const int r = wave * 2 + rr2;
            float a = 0.f;
            #pragma unroll
            for (int e = 0; e < D_N; ++e) a += dw[e] * sr[r * SEP + e];
            DR[lane * REL_N + r] = a;
        }
    }

    // DE: wave handles s-locals [wave*4, wave*4+4); se reads broadcast within 64-lane groups
    {
        float4 o;
        float* op = reinterpret_cast<float*>(&o);
        #pragma unroll
        for (int jj = 0; jj < 4; ++jj) {
            const int nl = wave * 4 + jj;
            const float4* xr = reinterpret_cast<const float4*>(&se[nl * SEP]);
            float a0 = 0.f, a1 = 0.f, a2 = 0.f, a3 = 0.f;
            #pragma unroll
            for (int i = 0; i < 32; i += 4) {
                float4 x0 = xr[i], x1 = xr[i + 1], x2 = xr[i + 2], x3 = xr[i + 3];
                a0 += dw[4*i+ 0]*x0.x + dw[4*i+ 1]*x0.y + dw[4*i+ 2]*x0.z + dw[4*i+ 3]*x0.w;
                a1 += dw[4*i+ 4]*x1.x + dw[4*i+ 5]*x1.y + dw[4*i+ 6]*x1.z + dw[4*i+ 7]*x1.w;
                a2 += dw[4*i+ 8]*x2.x + dw[4*i+ 9]*x2.y + dw[4*i+10]*x2.z + dw[4*i+11]*x2.w;
                a3 += dw[4*i+12]*x3.x + dw[4*i+13]*x3.y + dw[4*i+14]*x3.z + dw[4*i+15]*x3.w;
            }
            op[jj] = a0 + a1 + a2 + a3;
        }
        *reinterpret_cast<float4*>(DE + (size_t)lane * S_N + s0 + wave * 4) = o;
    }

    __syncthreads();   // rr ready

    // xinv: 128 threads, one (s-local, r) pair each
    if (tid < 128) {
        const int sl = tid >> 3, r = tid & 7;
        const float4* ev4 = reinterpret_cast<const float4*>(&se[sl * SEP]);
        const float4* rv4 = reinterpret_cast<const float4*>(&sr[r * SEP]);
        float ee = 0.f, er = 0.f;
        #pragma unroll
        for (int i = 0; i < 32; ++i) {
            float4 ev = ev4[i], rv = rv4[i];
            ee += dot4(ev, ev);
            er += dot4(ev, rv);
        }
        const float sq = ee + 2.f * er + rr[r];
        const bool m = (inputs[s0 + sl] != 0);
        xinv[(size_t)(s0 + sl) * REL_N + r] = (m && sq > 0.f) ? rsqrtf(sq) : 0.f;
    }
}

// block (kg, c): out rows kg*4..kg*4+3, cols [c*133120, (c+1)*133120) = h rows 4c..4c+3.
// 1024 streams of 520 KB (measured stream-count optimum: 2048 and 512 both worse).
// h synthesized inline from L2-resident xinv/DE/DR/rf; round-7 interleave; nt on w.
__global__ __launch_bounds__(512, 1) void k_mv(const float* __restrict__ fcw,
                                               const float* __restrict__ rf,
                                               const float* __restrict__ DE,
                                               const float* __restrict__ DR,
                                               const float* __restrict__ dsc_g,
                                               const float* __restrict__ xinv,
                                               float* __restrict__ partials) {
    const int tid = threadIdx.x;
    // bijective XCD swizzle (256 % 8 == 0): chunk c's 16 blocks cluster on one XCD
    const int swz = (blockIdx.x & 7) * (NBLK3 / 8) + (blockIdx.x >> 3);
    const int c  = swz >> 4;      // 0..15
    const int kg = swz & 15;      // 0..15

    const floatx4* wp = reinterpret_cast<const floatx4*>(fcw)
                        + (size_t)(kg * RPB) * (FC_IN_N / 4) + (size_t)c * NF4;
    const float4* xv4 = reinterpret_cast<const float4*>(xinv);

    float acc[RPB];
    #pragma unroll
    for (int j = 0; j < RPB; ++j) acc[j] = 0.f;

    #pragma unroll
    for (int half = 0; half < 4; ++half) {
        const int dd = 4 * c + half;
        const float dscv = dsc_g[dd];
        const float4 drlo = reinterpret_cast<const float4*>(DR)[dd * 2];
        const float4 drhi = reinterpret_cast<const float4*>(DR)[dd * 2 + 1];
        const float4 drv = (tid & 1) ? drhi : drlo;   // r-base = 4*(tid&1), thread-constant
        const float* DEp = DE + (size_t)dd * S_N;
        const int wbase = half * (ROWLEN / 4);        // half * 8320

        // rules columns: 128 f4 of this row
        if (tid < 128) {
            float4 hv = reinterpret_cast<const float4*>(rf)[dd * 128 + tid];
            const int idx = wbase + tid;
            #pragma unroll
            for (int j = 0; j < RPB; ++j) {
                floatx4 w = __builtin_nontemporal_load(wp + (size_t)j * (FC_IN_N / 4) + idx);
                acc[j] += w.x * hv.x + w.y * hv.y + w.z * hv.z + w.w * hv.w;
            }
        }

        // kg columns: exactly 16 x 512 f4 per row
        #pragma unroll 2
        for (int i = 0; i < 16; ++i) {
            const int col4k = i * 512 + tid;          // kg-local f4 index, 0..8191
            const int idx = wbase + 128 + col4k;
            const float de = DEp[col4k >> 1];         // s = n>>3 = col4k>>1
            const float4 xv = xv4[col4k];
            float4 hv;
            hv.x = dscv * xv.x * (de + drv.x);
            hv.y = dscv * xv.y * (de + drv.y);
            hv.z = dscv * xv.z * (de + drv.z);
            hv.w = dscv * xv.w * (de + drv.w);
            #pragma unroll
            for (int j = 0; j < RPB; ++j) {
                floatx4 w = __builtin_nontemporal_load(wp + (size_t)j * (FC_IN_N / 4) + idx);
                acc[j] += w.x * hv.x + w.y * hv.y + w.z * hv.z + w.w * hv.w;
            }
        }
    }

    #pragma unroll
    for (int m = 32; m >= 1; m >>= 1) {
        #pragma unroll
        for (int j = 0; j < RPB; ++j) acc[j] += __shfl_xor(acc[j], m);
    }
    __shared__ float red[8][RPB];
    if ((tid & 63) == 0) {
        const int wv = tid >> 6;
        #pragma unroll
        for (int j = 0; j < RPB; ++j) red[wv][j] = acc[j];
    }
    __syncthreads();
    if (tid < RPB) {
        float s = 0.f;
        #pragma unroll
        for (int wv = 0; wv < 8; ++wv) s += red[wv][tid];
        // partials[swz*RPB + j] == partials[c*64 + kg*4 + j]
        partials[(size_t)swz * RPB + tid] = s;
    }
}

// out[k] = sigmoid(fc_b[k] + sum_c partials[c*64 + k])
__global__ __launch_bounds__(256) void k_fin(const float* __restrict__ partials,
                                             const float* __restrict__ fcb,
                                             float* __restrict__ out) {
    const int tid = threadIdx.x;
    const int k = tid & 63, g = tid >> 6;
    float s = 0.f;
    for (int b = g; b < NCH; b += 4) s += partials[(size_t)b * 64 + k];
    __shared__ float red[4][64];
    red[g][k] = s;
    __syncthreads();
    if (tid < 64) {
        float t = red[0][tid] + red[1][tid] + red[2][tid] + red[3][tid] + fcb[tid];
        out[tid] = 1.0f / (1.0f + expf(-t));
    }
}

extern "C" void kernel_launch(void* const* d_in, const int* in_sizes, int n_in,
                              void* d_out, int out_size, void* d_ws, size_t ws_size,
                              hipStream_t stream) {
    const int*   inputs = (const int*)  d_in[0];
    const float* rf     = (const float*)d_in[1];
    const float* embed  = (const float*)d_in[2];
    const float* rel    = (const float*)d_in[3];
    const float* dise   = (const float*)d_in[4];
    const float* fcw    = (const float*)d_in[5];
    const float* fcb    = (const float*)d_in[6];
    float* out = (float*)d_out;

    // ws layout (floats): partials[NCH*64] | DE[64*4096] | DR[64*8] | dsc[64] | xinv[32768]
    float* ws = (float*)d_ws;
    float* partials = ws;
    float* DE       = partials + NCH * 64;
    float* DR       = DE + (size_t)DD_N * S_N;
    float* dsc_g    = DR + DD_N * REL_N;
    float* xinv     = dsc_g + 64;

    hipLaunchKernelGGL(k_pre, dim3(S_N / 16), dim3(256), 0, stream,
                       inputs, dise, embed, rel, DE, DR, dsc_g, xinv);
    hipLaunchKernelGGL(k_mv,  dim3(NBLK3),    dim3(512), 0, stream,
                       fcw, rf, DE, DR, dsc_g, xinv, partials);
    hipLaunchKernelGGL(k_fin, dim3(1),        dim3(256), 0, stream, partials, fcb, out);
}

// Round 16
// 98.315 us; speedup vs baseline: 1.0217x; 1.0033x over previous
//
#include <hip/hip_runtime.h>
#include <math.h>

namespace {
constexpr int S_N   = 4096;
constexpr int D_N   = 128;
constexpr int DD_N  = 64;
constexpr int REL_N = 8;
constexpr int R_N   = 512;
constexpr int NTOT  = S_N * REL_N;                        // 32768
constexpr int ROWLEN = R_N + NTOT;                        // 33280
constexpr long long FC_IN_N = (long long)DD_N * ROWLEN;   // 2,129,920
constexpr int NCH   = 16;                                 // col chunks per w-row (measured optimum)
constexpr int CHUNK2 = (int)(FC_IN_N / NCH);              // 133,120 floats = 520 KB = exactly 4 h-rows
constexpr int NF4   = CHUNK2 / 4;                         // 33,280 float4 per chunk (4 x 8320)
constexpr int RPB   = 4;                                  // output rows per k_mv block
constexpr int KG_N  = DD_N / RPB;                         // 16 k-groups
constexpr int NBLK3 = NCH * KG_N;                         // 256 blocks (1/CU, mult of 8)
constexpr int SEP   = 132;                                // padded LDS row stride (floats)
typedef float floatx4 __attribute__((ext_vector_type(4)));

__device__ __forceinline__ float dot4(const float4& a, const float4& b) {
    return a.x*b.x + a.y*b.y + a.z*b.z + a.w*b.w;
}
}

// Fused pre-kernel, 256 blocks x 16 symptoms each:
//   DE[dd][s] = dise[dd].embed[s]
//   xinv[s*8+r] = mask[s]&&sq>0 ? rsqrt(||e_s||^2 + 2 e_s.rel_r + ||rel_r||^2) : 0
//   block 0 also: dsc[dd]=1/||dise[dd]||, DR[dd][r]=dise[dd].rel[r]
__global__ __launch_bounds__(256) void k_pre(const int* __restrict__ inputs,
                                             const float* __restrict__ dise,
                                             const float* __restrict__ embed,
                                             const float* __restrict__ rel,
                                             float* __restrict__ DE,
                                             float* __restrict__ DR,
                                             float* __restrict__ dsc_g,
                                             float* __restrict__ xinv) {
    __shared__ float sd[DD_N * 129];                  // dise, pad 129 (2-way = free)
    __shared__ __align__(16) float se[16 * SEP];      // embed tile, stride 132 (conflict-free groups)
    __shared__ __align__(16) float sr[REL_N * SEP];   // rel, stride 132
    __shared__ float rr[REL_N];
    const int tid  = threadIdx.x;
    const int lane = tid & 63;
    const int wave = tid >> 6;
    const int s0   = blockIdx.x * 16;

    for (int i = tid; i < DD_N * D_N; i += 256)
        sd[(i >> 7) * 129 + (i & 127)] = dise[i];
    for (int i = tid; i < 16 * 32; i += 256) {        // 512 float4s of embed tile
        const int row = i >> 5, col = i & 31;
        *reinterpret_cast<float4*>(&se[row * SEP + col * 4]) =
            reinterpret_cast<const float4*>(embed + (size_t)s0 * D_N)[i];
    }
    if (tid < REL_N * 32) {                           // 256 float4s of rel
        const int row = tid >> 5, col = tid & 31;
        *reinterpret_cast<float4*>(&sr[row * SEP + col * 4]) =
            reinterpret_cast<const float4*>(rel)[tid];
    }
    __syncthreads();

    if (tid < REL_N) {
        float a = 0.f;
        for (int e = 0; e < D_N; ++e) { float v = sr[tid * SEP + e]; a += v * v; }
        rr[tid] = a;
    }

    float dw[D_N];
    float dsq = 0.f;
    #pragma unroll
    for (int e = 0; e < D_N; ++e) {
        dw[e] = sd[lane * 129 + e];
        dsq += dw[e] * dw[e];
    }
    const float dsc = rsqrtf(dsq);

    if (blockIdx.x == 0) {
        if (wave == 0) dsc_g[lane] = dsc;
        #pragma unroll
        for (int rr2 = 0; rr2 < 2; ++rr2) {
            const int r = wave * 2 + rr2;
            float a = 0.f;
            #pragma unroll
            for (int e = 0; e < D_N; ++e) a += dw[e] * sr[r * SEP + e];
            DR[lane * REL_N + r] = a;
        }
    }

    // DE: wave handles s-locals [wave*4, wave*4+4); se reads broadcast within 64-lane groups
    {
        float4 o;
        float* op = reinterpret_cast<float*>(&o);
        #pragma unroll
        for (int jj = 0; jj < 4; ++jj) {
            const int nl = wave * 4 + jj;
            const float4* xr = reinterpret_cast<const float4*>(&se[nl * SEP]);
            float a0 = 0.f, a1 = 0.f, a2 = 0.f, a3 = 0.f;
            #pragma unroll
            for (int i = 0; i < 32; i += 4) {
                float4 x0 = xr[i], x1 = xr[i + 1], x2 = xr[i + 2], x3 = xr[i + 3];
                a0 += dw[4*i+ 0]*x0.x + dw[4*i+ 1]*x0.y + dw[4*i+ 2]*x0.z + dw[4*i+ 3]*x0.w;
                a1 += dw[4*i+ 4]*x1.x + dw[4*i+ 5]*x1.y + dw[4*i+ 6]*x1.z + dw[4*i+ 7]*x1.w;
                a2 += dw[4*i+ 8]*x2.x + dw[4*i+ 9]*x2.y + dw[4*i+10]*x2.z + dw[4*i+11]*x2.w;
                a3 += dw[4*i+12]*x3.x + dw[4*i+13]*x3.y + dw[4*i+14]*x3.z + dw[4*i+15]*x3.w;
            }
            op[jj] = a0 + a1 + a2 + a3;
        }
        *reinterpret_cast<float4*>(DE + (size_t)lane * S_N + s0 + wave * 4) = o;
    }

    __syncthreads();   // rr ready

    // xinv: 128 threads, one (s-local, r) pair each
    if (tid < 128) {
        const int sl = tid >> 3, r = tid & 7;
        const float4* ev4 = reinterpret_cast<const float4*>(&se[sl * SEP]);
        const float4* rv4 = reinterpret_cast<const float4*>(&sr[r * SEP]);
        float ee = 0.f, er = 0.f;
        #pragma unroll
        for (int i = 0; i < 32; ++i) {
            float4 ev = ev4[i], rv = rv4[i];
            ee += dot4(ev, ev);
            er += dot4(ev, rv);
        }
        const float sq = ee + 2.f * er + rr[r];
        const bool m = (inputs[s0 + sl] != 0);
        xinv[(size_t)(s0 + sl) * REL_N + r] = (m && sq > 0.f) ? rsqrtf(sq) : 0.f;
    }
}

// block (kg, c): out rows kg*4..kg*4+3, cols [c*133120, (c+1)*133120) = h rows 4c..4c+3.
// 1024 streams of 520 KB (measured stream-count optimum: 2048 and 512 both worse).
// h synthesized inline from L2-resident xinv/DE/DR/rf; round-7 interleave; nt on w.
__global__ __launch_bounds__(512, 1) void k_mv(const float* __restrict__ fcw,
                                               const float* __restrict__ rf,
                                               const float* __restrict__ DE,
                                               const float* __restrict__ DR,
                                               const float* __restrict__ dsc_g,
                                               const float* __restrict__ xinv,
                                               float* __restrict__ partials) {
    const int tid = threadIdx.x;
    // bijective XCD swizzle (256 % 8 == 0): chunk c's 16 blocks cluster on one XCD
    const int swz = (blockIdx.x & 7) * (NBLK3 / 8) + (blockIdx.x >> 3);
    const int c  = swz >> 4;      // 0..15
    const int kg = swz & 15;      // 0..15

    const floatx4* wp = reinterpret_cast<const floatx4*>(fcw)
                        + (size_t)(kg * RPB) * (FC_IN_N / 4) + (size_t)c * NF4;
    const float4* xv4 = reinterpret_cast<const float4*>(xinv);

    float acc[RPB];
    #pragma unroll
    for (int j = 0; j < RPB; ++j) acc[j] = 0.f;

    #pragma unroll
    for (int half = 0; half < 4; ++half) {
        const int dd = 4 * c + half;
        const float dscv = dsc_g[dd];
        const float4 drlo = reinterpret_cast<const float4*>(DR)[dd * 2];
        const float4 drhi = reinterpret_cast<const float4*>(DR)[dd * 2 + 1];
        const float4 drv = (tid & 1) ? drhi : drlo;   // r-base = 4*(tid&1), thread-constant
        const float* DEp = DE + (size_t)dd * S_N;
        const int wbase = half * (ROWLEN / 4);        // half * 8320

        // rules columns: 128 f4 of this row
        if (tid < 128) {
            float4 hv = reinterpret_cast<const float4*>(rf)[dd * 128 + tid];
            const int idx = wbase + tid;
            #pragma unroll
            for (int j = 0; j < RPB; ++j) {
                floatx4 w = __builtin_nontemporal_load(wp + (size_t)j * (FC_IN_N / 4) + idx);
                acc[j] += w.x * hv.x + w.y * hv.y + w.z * hv.z + w.w * hv.w;
            }
        }

        // kg columns: exactly 16 x 512 f4 per row
        #pragma unroll 2
        for (int i = 0; i < 16; ++i) {
            const int col4k = i * 512 + tid;          // kg-local f4 index, 0..8191
            const int idx = wbase + 128 + col4k;
            const float de = DEp[col4k >> 1];         // s = n>>3 = col4k>>1
            const float4 xv = xv4[col4k];
            float4 hv;
            hv.x = dscv * xv.x * (de + drv.x);
            hv.y = dscv * xv.y * (de + drv.y);
            hv.z = dscv * xv.z * (de + drv.z);
            hv.w = dscv * xv.w * (de + drv.w);
            #pragma unroll
            for (int j = 0; j < RPB; ++j) {
                floatx4 w = __builtin_nontemporal_load(wp + (size_t)j * (FC_IN_N / 4) + idx);
                acc[j] += w.x * hv.x + w.y * hv.y + w.z * hv.z + w.w * hv.w;
            }
        }
    }

    #pragma unroll
    for (int m = 32; m >= 1; m >>= 1) {
        #pragma unroll
        for (int j = 0; j < RPB; ++j) acc[j] += __shfl_xor(acc[j], m);
    }
    __shared__ float red[8][RPB];
    if ((tid & 63) == 0) {
        const int wv = tid >> 6;
        #pragma unroll
        for (int j = 0; j < RPB; ++j) red[wv][j] = acc[j];
    }
    __syncthreads();
    if (tid < RPB) {
        float s = 0.f;
        #pragma unroll
        for (int wv = 0; wv < 8; ++wv) s += red[wv][tid];
        // partials[swz*RPB + j] == partials[c*64 + kg*4 + j]
        partials[(size_t)swz * RPB + tid] = s;
    }
}

// out[k] = sigmoid(fc_b[k] + sum_c partials[c*64 + k])
__global__ __launch_bounds__(256) void k_fin(const float* __restrict__ partials,
                                             const float* __restrict__ fcb,
                                             float* __restrict__ out) {
    const int tid = threadIdx.x;
    const int k = tid & 63, g = tid >> 6;
    float s = 0.f;
    for (int b = g; b < NCH; b += 4) s += partials[(size_t)b * 64 + k];
    __shared__ float red[4][64];
    red[g][k] = s;
    __syncthreads();
    if (tid < 64) {
        float t = red[0][tid] + red[1][tid] + red[2][tid] + red[3][tid] + fcb[tid];
        out[tid] = 1.0f / (1.0f + expf(-t));
    }
}

extern "C" void kernel_launch(void* const* d_in, const int* in_sizes, int n_in,
                              void* d_out, int out_size, void* d_ws, size_t ws_size,
                              hipStream_t stream) {
    const int*   inputs = (const int*)  d_in[0];
    const float* rf     = (const float*)d_in[1];
    const float* embed  = (const float*)d_in[2];
    const float* rel    = (const float*)d_in[3];
    const float* dise   = (const float*)d_in[4];
    const float* fcw    = (const float*)d_in[5];
    const float* fcb    = (const float*)d_in[6];
    float* out = (float*)d_out;

    // ws layout (floats): partials[NCH*64] | DE[64*4096] | DR[64*8] | dsc[64] | xinv[32768]
    float* ws = (float*)d_ws;
    float* partials = ws;
    float* DE       = partials + NCH * 64;
    float* DR       = DE + (size_t)DD_N * S_N;
    float* dsc_g    = DR + DD_N * REL_N;
    float* xinv     = dsc_g + 64;

    hipLaunchKernelGGL(k_pre, dim3(S_N / 16), dim3(256), 0, stream,
                       inputs, dise, embed, rel, DE, DR, dsc_g, xinv);
    hipLaunchKernelGGL(k_mv,  dim3(NBLK3),    dim3(512), 0, stream,
                       fcw, rf, DE, DR, dsc_g, xinv, partials);
    hipLaunchKernelGGL(k_fin, dim3(1),        dim3(256), 0, stream, partials, fcb, out);
}